// Round 5
// baseline (293.627 us; speedup 1.0000x reference)
//
#include <hip/hip_runtime.h>

// Problem constants: B=4, N=4096, V=4096, P=16, C=16, NK=4, L_MAX=2
#define N_DIM 4096

typedef float v2f __attribute__((ext_vector_type(2)));
typedef float v4f __attribute__((ext_vector_type(4)));

// v_pk_fma_f32 (VOP3P), encodings HW-verified in round 4 (passed):
// PK_AB  : acc += (s.lo*k.lo, s.lo*k.hi)   broadcast s.lo over k-pair
// PK_AB_H: acc += (s.hi*k.lo, s.hi*k.hi)   broadcast s.hi over k-pair
// PK_SB  : acc += (s.lo*k.lo, s.hi*k.lo)   broadcast k.lo over s-pair
// PK_SB_H: acc += (s.lo*k.hi, s.hi*k.hi)   broadcast k.hi over s-pair
#define PK_AB(acc, s, k)   asm("v_pk_fma_f32 %0, %1, %2, %0 op_sel:[0,0,0] op_sel_hi:[0,1,1]" : "+v"(acc) : "v"(s), "v"(k))
#define PK_AB_H(acc, s, k) asm("v_pk_fma_f32 %0, %1, %2, %0 op_sel:[1,0,0] op_sel_hi:[1,1,1]" : "+v"(acc) : "v"(s), "v"(k))
#define PK_SB(acc, s, k)   asm("v_pk_fma_f32 %0, %1, %2, %0 op_sel:[0,0,0] op_sel_hi:[1,0,1]" : "+v"(acc) : "v"(s), "v"(k))
#define PK_SB_H(acc, s, k) asm("v_pk_fma_f32 %0, %1, %2, %0 op_sel:[0,1,0] op_sel_hi:[1,1,1]" : "+v"(acc) : "v"(s), "v"(k))

// ---------------------------------------------------------------------------
// Compile-time Clebsch-Gordan coefficients (Racah formula, mirrors reference)
// ---------------------------------------------------------------------------
constexpr double cfac(int x){ double r=1.0; for(int i=2;i<=x;++i) r*=(double)i; return r; }
constexpr double csqrt_(double x){ double g = x>1.0? x:1.0; for(int i=0;i<200;++i) g=0.5*(g+x/g); return g; }
constexpr double cg_coef(int l,int m,int k,int n,int J,int M){
  if(M != m+n) return 0.0;
  if(n < -k || n > k) return 0.0;
  double pref = (double)(2*J+1)*cfac(l+k-J)*cfac(l-k+J)*cfac(-l+k+J)/cfac(l+k+J+1);
  pref *= cfac(J+M)*cfac(J-M)*cfac(l-m)*cfac(l+m)*cfac(k-n)*cfac(k+n);
  int tlo = 0;
  if(k-J-m > tlo) tlo = k-J-m;
  if(l+n-J > tlo) tlo = l+n-J;
  int thi = l+k-J;
  if(l-m < thi) thi = l-m;
  if(k+n < thi) thi = k+n;
  double s = 0.0;
  for(int t=tlo; t<=thi; ++t){
    double d = cfac(t)*cfac(l+k-J-t)*cfac(l-m-t)*cfac(k+n-t)*cfac(J-k+m+t)*cfac(J-l-n+t);
    s += ((t&1)? -1.0 : 1.0)/d;
  }
  return csqrt_(pref)*s;
}

template<int L_,int K_,int J_> struct QtabT { float a[2*J_+1][2*L_+1]; };
template<int L_,int K_,int J_>
constexpr QtabT<L_,K_,J_> make_q(){
  QtabT<L_,K_,J_> q{};
  for(int M=-J_;M<=J_;++M)
    for(int m=-L_;m<=L_;++m)
      q.a[M+J_][m+L_] = (float)cg_coef(L_,m,K_,M-m,J_,M);
  return q;
}

template<int L_,int K_,int J_,int W_,int CHOFF_>
__device__ __forceinline__ void cg_store(const float (&y)[2*L_+1][2*K_+1],
                                         float* __restrict__ o, size_t bvs, int lane){
  constexpr QtabT<L_,K_,J_> Q = make_q<L_,K_,J_>();
  #pragma unroll
  for(int Mi=0; Mi<2*J_+1; ++Mi){
    float acc = 0.f;
    #pragma unroll
    for(int mi=0; mi<2*L_+1; ++mi){
      const int ni = (Mi-J_) - (mi-L_) + K_;     // CG selection rule n = M-m
      if(ni < 0 || ni > 2*K_) continue;
      acc += Q.a[Mi][mi] * y[mi][ni];
    }
    o[(bvs*(2*J_+1) + (size_t)Mi)*W_ + CHOFF_ + lane] = acc;
  }
}

// ---------------------------------------------------------------------------
// ONE WAVE (64 threads) per (b,v). No barriers. Lane: n=lane>>4, c=lane&15.
// sig_lds[p][c][m0..8]  p-stride 196, c-stride 12 (m contiguous -> b128 reads;
//                       c,c+8 start-bank alias = 2-way = free)
// kern_t [p][n][kd0..8] p-stride 48, n-stride 12 (16-lane broadcast, no conflict)
// Main loop per p: 6 LDS reads + 42 v_pk_fma_f32 (all 81 m*kd products).
// ---------------------------------------------------------------------------
__global__ __launch_bounds__(64)
void conv_kernel(const float* __restrict__ sig0, const float* __restrict__ ker0,
                 const float* __restrict__ sig1, const float* __restrict__ ker1,
                 const float* __restrict__ sig2, const float* __restrict__ ker2,
                 const unsigned* __restrict__ pw, float* __restrict__ out){
  __shared__ __align__(16) float sig_lds[16*196];
  __shared__ __align__(16) float kern_t[16*48];

  const int lane = threadIdx.x;
  const int bv   = blockIdx.x;
  const size_t bvs = (size_t)bv;
  const int n = lane >> 4, c = lane & 15;

  // --- patch indices (register-only; int64-vs-int32 storage detect) ---
  int row = 0;
  {
    const unsigned probe = (lane < 16) ? pw[2*lane + 1] : 0u;
    const unsigned long long nz = __ballot(probe != 0u);
    const size_t s = (nz == 0ull) ? 2 : 1;          // 2 = int64, 1 = int32
    if(lane < 16){
      const size_t e = ((size_t)bv*16 + lane)*2;
      const int pb = (int)pw[(e+0)*s] & 3;
      const int pn = (int)pw[(e+1)*s] & (N_DIM-1);
      row = pb*N_DIM + pn;
    }
  }

  // --- stage kernels -> [p][n][12] ---
  {
    if(lane < 16){
      float4 v = ((const float4*)(ker0 + bvs*64))[lane];
      float* d = &kern_t[lane*48];
      d[0]=v.x; d[12]=v.y; d[24]=v.z; d[36]=v.w;
    }
    if(lane < 48){
      float4 v = ((const float4*)(ker1 + bvs*192))[lane];
      const int p = lane/3, kd = lane%3;
      float* d = &kern_t[p*48 + 1 + kd];
      d[0]=v.x; d[12]=v.y; d[24]=v.z; d[36]=v.w;
    }
    #pragma unroll
    for(int j=lane; j<80; j+=64){
      float4 v = ((const float4*)(ker2 + bvs*320))[j];
      const int p = j/5, kd = j%5;
      float* d = &kern_t[p*48 + 4 + kd];
      d[0]=v.x; d[12]=v.y; d[24]=v.z; d[36]=v.w;
    }
  }

  // --- gather signals -> [p][c][m]: lane (p=lane>>2, q=lane&3), 9 rounds ---
  {
    const int p = lane >> 2, q = lane & 3;
    const size_t ro = (size_t)__shfl(row, p);
    float* dst = sig_lds + p*196 + 4*q*12;   // c = 4q .. 4q+3
    const float4* r0 = (const float4*)(sig0 + ro*16);
    const float4* r1 = (const float4*)(sig1 + ro*48);
    const float4* r2 = (const float4*)(sig2 + ro*80);
#define WR4(v, mm) { dst[0*12+(mm)]=v.x; dst[1*12+(mm)]=v.y; dst[2*12+(mm)]=v.z; dst[3*12+(mm)]=v.w; }
    { float4 a=r0[q];    WR4(a,0); }
    { float4 a=r1[q];    WR4(a,1); }
    { float4 a=r1[q+4];  WR4(a,2); }
    { float4 a=r1[q+8];  WR4(a,3); }
    { float4 a=r2[q];    WR4(a,4); }
    { float4 a=r2[q+4];  WR4(a,5); }
    { float4 a=r2[q+8];  WR4(a,6); }
    { float4 a=r2[q+12]; WR4(a,7); }
    { float4 a=r2[q+16]; WR4(a,8); }
#undef WR4
  }
  // single wave: no __syncthreads needed; compiler inserts lgkmcnt waits.

  // --- main contraction: all 81 (m,kd) products, packed ---
  v2f t0[5], q1[5], u23[9], a45[9], a67[9], c8[5];
  #pragma unroll
  for(int i=0;i<5;++i){ t0[i]=(v2f){0,0}; q1[i]=(v2f){0,0}; c8[i]=(v2f){0,0}; }
  #pragma unroll
  for(int i=0;i<9;++i){ u23[i]=(v2f){0,0}; a45[i]=(v2f){0,0}; a67[i]=(v2f){0,0}; }

  #pragma unroll
  for(int p=0;p<16;++p){
    const float* sp = sig_lds + p*196 + c*12;
    const float* kp = kern_t  + p*48  + n*12;
    v4f sA = *(const v4f*)(sp);   v4f sB = *(const v4f*)(sp+4);  v2f sC = *(const v2f*)(sp+8);
    v4f kA = *(const v4f*)(kp);   v4f kB = *(const v4f*)(kp+4);  v2f kC = *(const v2f*)(kp+8);
    v2f s01=sA.xy, s23=sA.zw, s45=sB.xy, s67=sB.zw;
    v2f k01=kA.xy, k23=kA.zw, k45=kB.xy, k67=kB.zw;
    // kd0 (k01.lo) and kd1 (k01.hi) over m-pairs
    PK_SB  (t0[0], s01, k01); PK_SB  (t0[1], s23, k01); PK_SB  (t0[2], s45, k01);
    PK_SB  (t0[3], s67, k01); PK_SB  (t0[4], sC,  k01);
    PK_SB_H(q1[0], s01, k01); PK_SB_H(q1[1], s23, k01); PK_SB_H(q1[2], s45, k01);
    PK_SB_H(q1[3], s67, k01); PK_SB_H(q1[4], sC,  k01);
    // (kd2,kd3) per m
    PK_AB  (u23[0], s01, k23); PK_AB_H(u23[1], s01, k23);
    PK_AB  (u23[2], s23, k23); PK_AB_H(u23[3], s23, k23);
    PK_AB  (u23[4], s45, k23); PK_AB_H(u23[5], s45, k23);
    PK_AB  (u23[6], s67, k23); PK_AB_H(u23[7], s67, k23);
    PK_AB  (u23[8], sC,  k23);
    // (kd4,kd5) per m
    PK_AB  (a45[0], s01, k45); PK_AB_H(a45[1], s01, k45);
    PK_AB  (a45[2], s23, k45); PK_AB_H(a45[3], s23, k45);
    PK_AB  (a45[4], s45, k45); PK_AB_H(a45[5], s45, k45);
    PK_AB  (a45[6], s67, k45); PK_AB_H(a45[7], s67, k45);
    PK_AB  (a45[8], sC,  k45);
    // (kd6,kd7) per m
    PK_AB  (a67[0], s01, k67); PK_AB_H(a67[1], s01, k67);
    PK_AB  (a67[2], s23, k67); PK_AB_H(a67[3], s23, k67);
    PK_AB  (a67[4], s45, k67); PK_AB_H(a67[5], s45, k67);
    PK_AB  (a67[6], s67, k67); PK_AB_H(a67[7], s67, k67);
    PK_AB  (a67[8], sC,  k67);
    // kd8 (kC.lo) over m-pairs
    PK_SB  (c8[0], s01, kC);  PK_SB  (c8[1], s23, kC);  PK_SB  (c8[2], s45, kC);
    PK_SB  (c8[3], s67, kC);  PK_SB  (c8[4], sC,  kC);
  }

  // --- unpack to y[m][kd] ---
  float y[9][9];
  #pragma unroll
  for(int m=0;m<9;++m){
    y[m][0] = (m<8) ? ((m&1)? t0[m>>1].y : t0[m>>1].x) : t0[4].x;
    y[m][1] = (m<8) ? ((m&1)? q1[m>>1].y : q1[m>>1].x) : q1[4].x;
    y[m][2] = u23[m].x;  y[m][3] = u23[m].y;
    y[m][4] = a45[m].x;  y[m][5] = a45[m].y;
    y[m][6] = a67[m].x;  y[m][7] = a67[m].y;
    y[m][8] = (m<8) ? ((m&1)? c8[m>>1].y : c8[m>>1].x) : c8[4].x;
  }

  // --- outputs ---
  float* o0 = out;                 // [BV][1][192]
  float* o1 = out + 3145728;       // [BV][3][384]
  float* o2 = out + 22020096;      // [BV][5][384]

  // l=0 direct
  o0[bvs*192 + lane] = y[0][0];
  #pragma unroll
  for(int kd=0;kd<3;++kd) o1[(bvs*3 + kd)*384 + lane] = y[0][1+kd];
  #pragma unroll
  for(int kd=0;kd<5;++kd) o2[(bvs*5 + kd)*384 + lane] = y[0][4+kd];

  // sub-blocks
  float y10[3][1], y20[5][1], y11[3][3], y21[5][3], y12[3][5], y22[5][5];
  #pragma unroll
  for(int i=0;i<3;++i){
    y10[i][0]=y[1+i][0];
    #pragma unroll
    for(int j=0;j<3;++j) y11[i][j]=y[1+i][1+j];
    #pragma unroll
    for(int j=0;j<5;++j) y12[i][j]=y[1+i][4+j];
  }
  #pragma unroll
  for(int i=0;i<5;++i){
    y20[i][0]=y[4+i][0];
    #pragma unroll
    for(int j=0;j<3;++j) y21[i][j]=y[4+i][1+j];
    #pragma unroll
    for(int j=0;j<5;++j) y22[i][j]=y[4+i][4+j];
  }

  cg_store<1,0,1,384, 64>(y10, o1, bvs, lane);
  cg_store<2,0,2,384,192>(y20, o2, bvs, lane);
  cg_store<1,1,0,192, 64>(y11, o0, bvs, lane);
  cg_store<1,1,1,384,128>(y11, o1, bvs, lane);
  cg_store<1,1,2,384, 64>(y11, o2, bvs, lane);
  cg_store<2,1,1,384,256>(y21, o1, bvs, lane);
  cg_store<2,1,2,384,256>(y21, o2, bvs, lane);
  cg_store<1,2,1,384,192>(y12, o1, bvs, lane);
  cg_store<1,2,2,384,128>(y12, o2, bvs, lane);
  cg_store<2,2,0,192,128>(y22, o0, bvs, lane);
  cg_store<2,2,1,384,320>(y22, o1, bvs, lane);
  cg_store<2,2,2,384,320>(y22, o2, bvs, lane);
}

extern "C" void kernel_launch(void* const* d_in, const int* in_sizes, int n_in,
                              void* d_out, int out_size, void* d_ws, size_t ws_size,
                              hipStream_t stream) {
  const float *s0=nullptr,*s1=nullptr,*s2=nullptr,*k0=nullptr,*k1=nullptr,*k2=nullptr;
  const void* pidx=nullptr;
  if(n_in >= 7){
    s0=(const float*)d_in[0]; k0=(const float*)d_in[1];
    s1=(const float*)d_in[2]; k1=(const float*)d_in[3];
    s2=(const float*)d_in[4]; k2=(const float*)d_in[5];
    pidx=d_in[6];
  }
  for(int i=0;i<n_in;++i){
    switch(in_sizes[i]){
      case 262144:  s0=(const float*)d_in[i]; break;   // 4*4096*1*16
      case 786432:  s1=(const float*)d_in[i]; break;   // 4*4096*3*16
      case 1310720: s2=(const float*)d_in[i]; break;   // 4*4096*5*16
      case 1048576: k0=(const float*)d_in[i]; break;   // 4*4096*16*1*4
      case 3145728: k1=(const float*)d_in[i]; break;   // 4*4096*16*3*4
      case 5242880: k2=(const float*)d_in[i]; break;   // 4*4096*16*5*4
      case 524288:  pidx=d_in[i]; break;               // 4*4096*16*2
      default: break;
    }
  }

  conv_kernel<<<16384, 64, 0, stream>>>(s0, k0, s1, k1, s2, k2,
                                        (const unsigned*)pidx, (float*)d_out);
}